// Round 9
// baseline (265.899 us; speedup 1.0000x reference)
//
#include <hip/hip_runtime.h>
#include <stdint.h>

#define C_CH 128
#define SCAN_THREADS 256
#define SCAN_PER_THREAD 8
#define SCAN_ELEMS (SCAN_THREADS * SCAN_PER_THREAD)   // 2048
#define SPG 8                                         // segments per 32-lane group

typedef float floatx4 __attribute__((ext_vector_type(4)));

// ---------------- fallback (atomic) helpers ----------------
__device__ __forceinline__ unsigned fkey(float x) {
  unsigned b = __float_as_uint(x);
  return b ^ ((unsigned)((int)b >> 31) | 0x80000000u);
}
__device__ __forceinline__ float fdec(unsigned k) {
  unsigned b = (k & 0x80000000u) ? (k & 0x7FFFFFFFu) : ~k;
  return __uint_as_float(b);
}

__global__ __launch_bounds__(256) void pool_atomic(
    const float4* __restrict__ in4, const int* __restrict__ vt_replace,
    const int* __restrict__ vt_map, unsigned* __restrict__ outk, int64_t n4) {
  const int64_t stride = (int64_t)gridDim.x * blockDim.x;
  for (int64_t t = (int64_t)blockIdx.x * blockDim.x + threadIdx.x; t < n4;
       t += stride) {
    const int row = (int)(t >> 5);
    const int c4  = (int)(t & 31);
    int s = 0;
    if ((threadIdx.x & 31) == 0) s = vt_map[vt_replace[row]];
    s = __shfl(s, 0, 32);
    const float4 v = in4[t];
    unsigned* o = outk + ((int64_t)s << 7) + (c4 << 2);
    atomicMax(o + 0, fkey(v.x));
    atomicMax(o + 1, fkey(v.y));
    atomicMax(o + 2, fkey(v.z));
    atomicMax(o + 3, fkey(v.w));
  }
}
__global__ __launch_bounds__(256) void decode_k(unsigned* __restrict__ io, int64_t n4) {
  const int64_t stride = (int64_t)gridDim.x * blockDim.x;
  for (int64_t t = (int64_t)blockIdx.x * blockDim.x + threadIdx.x; t < n4;
       t += stride) {
    uint4* p = ((uint4*)io) + t;
    uint4 k = *p;
    float4 f;
    f.x = k.x ? fdec(k.x) : 0.0f;
    f.y = k.y ? fdec(k.y) : 0.0f;
    f.z = k.z ? fdec(k.z) : 0.0f;
    f.w = k.w ? fdec(k.w) : 0.0f;
    *(float4*)p = f;
  }
}

// ---------------- CSR path (R5-proven index build) ----------------

__global__ __launch_bounds__(256) void zero_u32(unsigned* __restrict__ p, int m) {
  const int stride = gridDim.x * blockDim.x;
  for (int i = blockIdx.x * blockDim.x + threadIdx.x; i < m; i += stride)
    p[i] = 0u;
}

__global__ __launch_bounds__(256) void seg_hist(
    const int* __restrict__ vt_replace, const int* __restrict__ vt_map,
    unsigned* __restrict__ counts, int n) {
  const int stride = gridDim.x * blockDim.x;
  for (int i = blockIdx.x * blockDim.x + threadIdx.x; i < n; i += stride) {
    const int s = vt_map[vt_replace[i]];
    atomicAdd(&counts[s], 1u);
  }
}

__global__ __launch_bounds__(SCAN_THREADS) void scan_reduce(
    const unsigned* __restrict__ counts, unsigned* __restrict__ bsums, int m) {
  __shared__ unsigned tot[SCAN_THREADS];
  const int base = blockIdx.x * SCAN_ELEMS + threadIdx.x * SCAN_PER_THREAD;
  unsigned s = 0;
  for (int j = 0; j < SCAN_PER_THREAD; ++j) {
    const int i = base + j;
    s += (i < m) ? counts[i] : 0u;
  }
  tot[threadIdx.x] = s;
  __syncthreads();
  for (int off = SCAN_THREADS / 2; off > 0; off >>= 1) {
    if (threadIdx.x < off) tot[threadIdx.x] += tot[threadIdx.x + off];
    __syncthreads();
  }
  if (threadIdx.x == 0) bsums[blockIdx.x] = tot[0];
}

__global__ void scan_bsums(unsigned* __restrict__ bsums, int g) {
  if (blockIdx.x == 0 && threadIdx.x == 0) {
    unsigned run = 0;
    for (int i = 0; i < g; ++i) { const unsigned t = bsums[i]; bsums[i] = run; run += t; }
  }
}

__global__ __launch_bounds__(SCAN_THREADS) void scan_down(
    const unsigned* __restrict__ counts, const unsigned* __restrict__ bsums,
    unsigned* __restrict__ cursor, int m) {
  __shared__ unsigned tot[SCAN_THREADS];
  const int base = blockIdx.x * SCAN_ELEMS + threadIdx.x * SCAN_PER_THREAD;
  unsigned v[SCAN_PER_THREAD];
  unsigned s = 0;
  for (int j = 0; j < SCAN_PER_THREAD; ++j) {
    const int i = base + j;
    v[j] = (i < m) ? counts[i] : 0u;
    s += v[j];
  }
  tot[threadIdx.x] = s;
  __syncthreads();
  for (int off = 1; off < SCAN_THREADS; off <<= 1) {
    unsigned t = (threadIdx.x >= (unsigned)off) ? tot[threadIdx.x - off] : 0u;
    __syncthreads();
    tot[threadIdx.x] += t;
    __syncthreads();
  }
  unsigned excl = (threadIdx.x ? tot[threadIdx.x - 1] : 0u) + bsums[blockIdx.x];
  for (int j = 0; j < SCAN_PER_THREAD; ++j) {
    const int i = base + j;
    if (i < m) cursor[i] = excl;
    excl += v[j];
  }
}

__global__ __launch_bounds__(256) void scatter_rows(
    const int* __restrict__ vt_replace, const int* __restrict__ vt_map,
    unsigned* __restrict__ cursor, int* __restrict__ rowids, int n) {
  const int stride = gridDim.x * blockDim.x;
  for (int i = blockIdx.x * blockDim.x + threadIdx.x; i < n; i += stride) {
    const int s = vt_map[vt_replace[i]];
    const unsigned p = atomicAdd(&cursor[s], 1u);
    rowids[p] = i;
  }
}

// Pass D: one 32-lane group per 8 SEGMENTS. All 8 (end,cnt) pairs load
// upfront (one L2 exposure amortized 8x); segment k+1's rowid chunk is
// ISSUED before segment k's row loads are consumed, so its L2 latency
// hides under the HBM row phase. Inner row loop = R5's proven
// split-unroll-4 + serial tail (exact cnt loads, no redundancy).
__device__ __forceinline__ floatx4 fmax4(floatx4 a, floatx4 b) {
  floatx4 r;
  r.x = fmaxf(a.x, b.x);
  r.y = fmaxf(a.y, b.y);
  r.z = fmaxf(a.z, b.z);
  r.w = fmaxf(a.w, b.w);
  return r;
}

__global__ __launch_bounds__(256) void gather_max8(
    const floatx4* __restrict__ in4, const int* __restrict__ rowids,
    const unsigned* __restrict__ cursor_end, const unsigned* __restrict__ counts,
    floatx4* __restrict__ out4, int m) {
  const int g = blockIdx.x * 8 + (threadIdx.x >> 5);   // 8 groups/block
  const int q = threadIdx.x & 31;                      // floatx4 slot in row
  const int sBase = g * SPG;
  if (sBase >= m) return;

  // 8 independent (end,cnt) pairs — all issued back-to-back, one L2 wait.
  unsigned end8[SPG], cnt8[SPG];
#pragma unroll
  for (int k = 0; k < SPG; ++k) {
    const int s = sBase + k;
    end8[k] = (s < m) ? cursor_end[s] : 0u;
    cnt8[k] = (s < m) ? counts[s] : 0u;
  }

  // prefetch segment 0's first rowid chunk
  int rid_cur = 0;
  {
    const unsigned c0 = cnt8[0];
    if (c0 && q < (int)min(c0, 32u)) rid_cur = rowids[(end8[0] - c0) + q];
  }

#pragma unroll
  for (int k = 0; k < SPG; ++k) {
    const int s = sBase + k;
    if (s >= m) break;
    const unsigned end = end8[k];
    const unsigned cnt = cnt8[k];
    const unsigned start = end - cnt;

    // issue next segment's rowid chunk NOW — latency hides under row loads
    int rid_next = 0;
    if (k + 1 < SPG) {
      const unsigned cn = cnt8[k + 1];
      if (cn && q < (int)min(cn, 32u)) rid_next = rowids[(end8[k + 1] - cn) + q];
    }

    floatx4 acc = (floatx4)(-INFINITY);
    for (unsigned base = start; base < end; base += 32) {
      const int nn = (int)min(32u, end - base);
      int rid;
      if (base == start) {
        rid = rid_cur;                       // prefetched
      } else {
        rid = 0;
        if (q < nn) rid = rowids[base + q];  // rare (cnt>32)
      }
      int j = 0;
      for (; j + 4 <= nn; j += 4) {          // 4 x 512B rows in flight
        const int r0 = __shfl(rid, j + 0, 32);
        const int r1 = __shfl(rid, j + 1, 32);
        const int r2 = __shfl(rid, j + 2, 32);
        const int r3 = __shfl(rid, j + 3, 32);
        const floatx4 v0 = __builtin_nontemporal_load(&in4[(int64_t)r0 * 32 + q]);
        const floatx4 v1 = __builtin_nontemporal_load(&in4[(int64_t)r1 * 32 + q]);
        const floatx4 v2 = __builtin_nontemporal_load(&in4[(int64_t)r2 * 32 + q]);
        const floatx4 v3 = __builtin_nontemporal_load(&in4[(int64_t)r3 * 32 + q]);
        acc = fmax4(acc, fmax4(fmax4(v0, v1), fmax4(v2, v3)));
      }
      for (; j < nn; ++j) {
        const int r = __shfl(rid, j, 32);
        const floatx4 v = __builtin_nontemporal_load(&in4[(int64_t)r * 32 + q]);
        acc = fmax4(acc, v);
      }
    }
    if (cnt == 0) acc = (floatx4)(0.0f);     // empty segment -> zeros
    __builtin_nontemporal_store(acc, &out4[(int64_t)s * 32 + q]);
    rid_cur = rid_next;
  }
}

// ---------------- launch ----------------
extern "C" void kernel_launch(void* const* d_in, const int* in_sizes, int n_in_args,
                              void* d_out, int out_size, void* d_ws, size_t ws_size,
                              hipStream_t stream) {
  (void)n_in_args;
  const float*  in         = (const float*)d_in[0];
  const int*    vt_replace = (const int*)d_in[1];
  const int*    vt_map     = (const int*)d_in[2];
  const int     n_in = in_sizes[1];
  const int     m    = out_size / C_CH;          // N_OUT

  // workspace carve (256B aligned)
  uintptr_t p = (uintptr_t)d_ws;
  auto carve = [&](size_t bytes) {
    uintptr_t r = p;
    p += (bytes + 255) & ~(size_t)255;
    return (void*)r;
  };
  int*      rowids = (int*)carve((size_t)n_in * 4);
  unsigned* counts = (unsigned*)carve((size_t)m * 4);
  unsigned* cursor = (unsigned*)carve((size_t)m * 4);
  unsigned* bsums  = (unsigned*)carve(4096);
  const size_t needed = p - (uintptr_t)d_ws;

  if (ws_size < needed) {
    unsigned* outk = (unsigned*)d_out;
    (void)hipMemsetAsync(d_out, 0, (size_t)out_size * sizeof(float), stream);
    const int64_t n4 = (int64_t)n_in * (C_CH / 4);
    pool_atomic<<<2048, 256, 0, stream>>>((const float4*)in, vt_replace, vt_map, outk, n4);
    decode_k<<<2048, 256, 0, stream>>>(outk, (int64_t)out_size / 4);
    return;
  }

  zero_u32<<<256, 256, 0, stream>>>(counts, m);

  seg_hist<<<2048, 256, 0, stream>>>(vt_replace, vt_map, counts, n_in);

  const int g1 = (m + SCAN_ELEMS - 1) / SCAN_ELEMS;   // ~123 for 250k
  scan_reduce<<<g1, SCAN_THREADS, 0, stream>>>(counts, bsums, m);
  scan_bsums<<<1, 64, 0, stream>>>(bsums, g1);
  scan_down<<<g1, SCAN_THREADS, 0, stream>>>(counts, bsums, cursor, m);

  scatter_rows<<<2048, 256, 0, stream>>>(vt_replace, vt_map, cursor, rowids, n_in);

  const int groups = (m + SPG - 1) / SPG;             // 31250
  gather_max8<<<(groups + 7) / 8, 256, 0, stream>>>(
      (const floatx4*)in, rowids, cursor, counts, (floatx4*)d_out, m);
}

// Round 10
// 235.179 us; speedup vs baseline: 1.1306x; 1.1306x over previous
//
#include <hip/hip_runtime.h>
#include <stdint.h>

#define C_CH 128
#define SCAN_THREADS 256
#define SCAN_PER_THREAD 8
#define SCAN_ELEMS (SCAN_THREADS * SCAN_PER_THREAD)   // 2048

typedef float floatx4 __attribute__((ext_vector_type(4)));

// ---------------- fallback (atomic) helpers ----------------
__device__ __forceinline__ unsigned fkey(float x) {
  unsigned b = __float_as_uint(x);
  return b ^ ((unsigned)((int)b >> 31) | 0x80000000u);
}
__device__ __forceinline__ float fdec(unsigned k) {
  unsigned b = (k & 0x80000000u) ? (k & 0x7FFFFFFFu) : ~k;
  return __uint_as_float(b);
}

__global__ __launch_bounds__(256) void pool_atomic(
    const float4* __restrict__ in4, const int* __restrict__ vt_replace,
    const int* __restrict__ vt_map, unsigned* __restrict__ outk, int64_t n4) {
  const int64_t stride = (int64_t)gridDim.x * blockDim.x;
  for (int64_t t = (int64_t)blockIdx.x * blockDim.x + threadIdx.x; t < n4;
       t += stride) {
    const int row = (int)(t >> 5);
    const int c4  = (int)(t & 31);
    int s = 0;
    if ((threadIdx.x & 31) == 0) s = vt_map[vt_replace[row]];
    s = __shfl(s, 0, 32);
    const float4 v = in4[t];
    unsigned* o = outk + ((int64_t)s << 7) + (c4 << 2);
    atomicMax(o + 0, fkey(v.x));
    atomicMax(o + 1, fkey(v.y));
    atomicMax(o + 2, fkey(v.z));
    atomicMax(o + 3, fkey(v.w));
  }
}
__global__ __launch_bounds__(256) void decode_k(unsigned* __restrict__ io, int64_t n4) {
  const int64_t stride = (int64_t)gridDim.x * blockDim.x;
  for (int64_t t = (int64_t)blockIdx.x * blockDim.x + threadIdx.x; t < n4;
       t += stride) {
    uint4* p = ((uint4*)io) + t;
    uint4 k = *p;
    float4 f;
    f.x = k.x ? fdec(k.x) : 0.0f;
    f.y = k.y ? fdec(k.y) : 0.0f;
    f.z = k.z ? fdec(k.z) : 0.0f;
    f.w = k.w ? fdec(k.w) : 0.0f;
    *(float4*)p = f;
  }
}

// ---------------- CSR path ----------------

__global__ __launch_bounds__(256) void zero_u32(unsigned* __restrict__ p, int m) {
  const int stride = gridDim.x * blockDim.x;
  for (int i = blockIdx.x * blockDim.x + threadIdx.x; i < m; i += stride)
    p[i] = 0u;
}

// Pass A: histogram of seg = vt_map[vt_replace[i]].
__global__ __launch_bounds__(256) void seg_hist(
    const int* __restrict__ vt_replace, const int* __restrict__ vt_map,
    unsigned* __restrict__ counts, int n) {
  const int stride = gridDim.x * blockDim.x;
  for (int i = blockIdx.x * blockDim.x + threadIdx.x; i < n; i += stride) {
    const int s = vt_map[vt_replace[i]];
    atomicAdd(&counts[s], 1u);
  }
}

// Scan 1: per-block (2048-elem) totals.
__global__ __launch_bounds__(SCAN_THREADS) void scan_reduce(
    const unsigned* __restrict__ counts, unsigned* __restrict__ bsums, int m) {
  __shared__ unsigned tot[SCAN_THREADS];
  const int base = blockIdx.x * SCAN_ELEMS + threadIdx.x * SCAN_PER_THREAD;
  unsigned s = 0;
  for (int j = 0; j < SCAN_PER_THREAD; ++j) {
    const int i = base + j;
    s += (i < m) ? counts[i] : 0u;
  }
  tot[threadIdx.x] = s;
  __syncthreads();
  for (int off = SCAN_THREADS / 2; off > 0; off >>= 1) {
    if (threadIdx.x < off) tot[threadIdx.x] += tot[threadIdx.x + off];
    __syncthreads();
  }
  if (threadIdx.x == 0) bsums[blockIdx.x] = tot[0];
}

// Scan 2: serial exclusive scan of block sums (g <= ~128).
__global__ void scan_bsums(unsigned* __restrict__ bsums, int g) {
  if (blockIdx.x == 0 && threadIdx.x == 0) {
    unsigned run = 0;
    for (int i = 0; i < g; ++i) { const unsigned t = bsums[i]; bsums[i] = run; run += t; }
  }
}

// Scan 3: write exclusive prefix (cursor = start offsets).
__global__ __launch_bounds__(SCAN_THREADS) void scan_down(
    const unsigned* __restrict__ counts, const unsigned* __restrict__ bsums,
    unsigned* __restrict__ cursor, int m) {
  __shared__ unsigned tot[SCAN_THREADS];
  const int base = blockIdx.x * SCAN_ELEMS + threadIdx.x * SCAN_PER_THREAD;
  unsigned v[SCAN_PER_THREAD];
  unsigned s = 0;
  for (int j = 0; j < SCAN_PER_THREAD; ++j) {
    const int i = base + j;
    v[j] = (i < m) ? counts[i] : 0u;
    s += v[j];
  }
  tot[threadIdx.x] = s;
  __syncthreads();
  for (int off = 1; off < SCAN_THREADS; off <<= 1) {
    unsigned t = (threadIdx.x >= (unsigned)off) ? tot[threadIdx.x - off] : 0u;
    __syncthreads();
    tot[threadIdx.x] += t;
    __syncthreads();
  }
  unsigned excl = (threadIdx.x ? tot[threadIdx.x - 1] : 0u) + bsums[blockIdx.x];
  for (int j = 0; j < SCAN_PER_THREAD; ++j) {
    const int i = base + j;
    if (i < m) cursor[i] = excl;
    excl += v[j];
  }
}

// Pass B: scatter row ids (seg recomputed; vt_map is L2-resident).
__global__ __launch_bounds__(256) void scatter_rows(
    const int* __restrict__ vt_replace, const int* __restrict__ vt_map,
    unsigned* __restrict__ cursor, int* __restrict__ rowids, int n) {
  const int stride = gridDim.x * blockDim.x;
  for (int i = blockIdx.x * blockDim.x + threadIdx.x; i < n; i += stride) {
    const int s = vt_map[vt_replace[i]];
    const unsigned p = atomicAdd(&cursor[s], 1u);
    rowids[p] = i;
  }
}

// Pass C: one 32-lane group per segment; lane owns 4 channels (floatx4).
// One load instruction = one full 512B row per group (two rows per wave).
__device__ __forceinline__ floatx4 fmax4(floatx4 a, floatx4 b) {
  floatx4 r;
  r.x = fmaxf(a.x, b.x);
  r.y = fmaxf(a.y, b.y);
  r.z = fmaxf(a.z, b.z);
  r.w = fmaxf(a.w, b.w);
  return r;
}

__global__ __launch_bounds__(256) void gather_max4(
    const floatx4* __restrict__ in4, const int* __restrict__ rowids,
    const unsigned* __restrict__ cursor_end, const unsigned* __restrict__ counts,
    floatx4* __restrict__ out4, int m) {
  const int s = blockIdx.x * 8 + (threadIdx.x >> 5);   // 8 groups/block
  if (s >= m) return;
  const int q = threadIdx.x & 31;                      // floatx4 slot in row
  const unsigned end = cursor_end[s];
  const unsigned cnt = counts[s];
  const unsigned start = end - cnt;

  floatx4 acc = (floatx4)(-INFINITY);

  for (unsigned base = start; base < end; base += 32) {
    const int nn = (int)min(32u, end - base);
    int rid = 0;
    if (q < nn) rid = rowids[base + q];      // one coalesced rowid load/group
    int j = 0;
    for (; j + 4 <= nn; j += 4) {            // 4 rows in flight (2KB/group)
      const int r0 = __shfl(rid, j + 0, 32);
      const int r1 = __shfl(rid, j + 1, 32);
      const int r2 = __shfl(rid, j + 2, 32);
      const int r3 = __shfl(rid, j + 3, 32);
      const floatx4 v0 = __builtin_nontemporal_load(&in4[(int64_t)r0 * 32 + q]);
      const floatx4 v1 = __builtin_nontemporal_load(&in4[(int64_t)r1 * 32 + q]);
      const floatx4 v2 = __builtin_nontemporal_load(&in4[(int64_t)r2 * 32 + q]);
      const floatx4 v3 = __builtin_nontemporal_load(&in4[(int64_t)r3 * 32 + q]);
      acc = fmax4(acc, fmax4(fmax4(v0, v1), fmax4(v2, v3)));
    }
    for (; j < nn; ++j) {
      const int r = __shfl(rid, j, 32);
      const floatx4 v = __builtin_nontemporal_load(&in4[(int64_t)r * 32 + q]);
      acc = fmax4(acc, v);
    }
  }
  if (cnt == 0) acc = (floatx4)(0.0f);
  __builtin_nontemporal_store(acc, &out4[(int64_t)s * 32 + q]);
}

// ---------------- launch ----------------
extern "C" void kernel_launch(void* const* d_in, const int* in_sizes, int n_in_args,
                              void* d_out, int out_size, void* d_ws, size_t ws_size,
                              hipStream_t stream) {
  (void)n_in_args;
  const float*  in         = (const float*)d_in[0];
  const int*    vt_replace = (const int*)d_in[1];
  const int*    vt_map     = (const int*)d_in[2];
  const int     n_in = in_sizes[1];
  const int     m    = out_size / C_CH;          // N_OUT

  // workspace carve (256B aligned)
  uintptr_t p = (uintptr_t)d_ws;
  auto carve = [&](size_t bytes) {
    uintptr_t r = p;
    p += (bytes + 255) & ~(size_t)255;
    return (void*)r;
  };
  int*      rowids = (int*)carve((size_t)n_in * 4);
  unsigned* counts = (unsigned*)carve((size_t)m * 4);
  unsigned* cursor = (unsigned*)carve((size_t)m * 4);
  unsigned* bsums  = (unsigned*)carve(4096);
  const size_t needed = p - (uintptr_t)d_ws;

  if (ws_size < needed) {
    unsigned* outk = (unsigned*)d_out;
    (void)hipMemsetAsync(d_out, 0, (size_t)out_size * sizeof(float), stream);
    const int64_t n4 = (int64_t)n_in * (C_CH / 4);
    pool_atomic<<<2048, 256, 0, stream>>>((const float4*)in, vt_replace, vt_map, outk, n4);
    decode_k<<<2048, 256, 0, stream>>>(outk, (int64_t)out_size / 4);
    return;
  }

  zero_u32<<<256, 256, 0, stream>>>(counts, m);

  seg_hist<<<2048, 256, 0, stream>>>(vt_replace, vt_map, counts, n_in);

  const int g1 = (m + SCAN_ELEMS - 1) / SCAN_ELEMS;   // ~123 for 250k
  scan_reduce<<<g1, SCAN_THREADS, 0, stream>>>(counts, bsums, m);
  scan_bsums<<<1, 64, 0, stream>>>(bsums, g1);
  scan_down<<<g1, SCAN_THREADS, 0, stream>>>(counts, bsums, cursor, m);

  scatter_rows<<<2048, 256, 0, stream>>>(vt_replace, vt_map, cursor, rowids, n_in);

  const int gc = (m + 7) / 8;   // 8 groups (segments) per block
  gather_max4<<<gc, 256, 0, stream>>>((const floatx4*)in, rowids, cursor, counts,
                                      (floatx4*)d_out, m);
}